// Round 9
// baseline (572.876 us; speedup 1.0000x reference)
//
#include <hip/hip_runtime.h>
#include <hip/hip_bf16.h>
#include <cstdint>
#include <cstddef>

// ---------------------------------------------------------------------------
// FlowformerLayer: LN1 -> flow-attention(batch0) -> +res -> LN2 -> MLP -> +res
// B=2, L=16384, D=512, H=8, DH=64, F=2048
// GEMM: 128x128 tile, BK=64, 4 waves, 32x32x16 MFMA (2x FLOP per fragment
// pair vs 16x16x32 -> halves LDS-read per FLOP; faster pipe per m119),
// double-buffered 64KB LDS, 1 barrier/K-tile, 2 blocks/CU.
// LDS rows = 64 elems (128B) with chunk-XOR swizzle slot=c^(r&7) — the
// R2-R5-verified ZERO-conflict scheme (8 lanes/16B-slot = exact minimum).
// 32-elem-row layouts (R1/R6/R7/R8) all measured 4-way conflicts (2^23 cyc).
// Attention chain: 3 passes over bf16 q/k + f32 v, slab-reduced (no atomics).
// ---------------------------------------------------------------------------

#define L_SEQ 16384
#define EPSF 1e-6f

typedef __bf16 b16x8 __attribute__((ext_vector_type(8)));
typedef __bf16 b16x4 __attribute__((ext_vector_type(4)));
typedef float  f32x4 __attribute__((ext_vector_type(4)));
typedef float  f32x16 __attribute__((ext_vector_type(16)));

#define FENCE() asm volatile("" ::: "memory")
#define BARF()  { FENCE(); __builtin_amdgcn_s_barrier(); FENCE(); }
#define WAITV(n) asm volatile("s_waitcnt vmcnt(" #n ")" ::: "memory")

__device__ __forceinline__ void gload16(const void* g, void* l) {
  __builtin_amdgcn_global_load_lds((const __attribute__((address_space(1))) void*)g,
                                   (__attribute__((address_space(3))) void*)l, 16, 0, 0);
}

__device__ __forceinline__ float sigmoidf_(float x) { return 1.f / (1.f + __expf(-x)); }

// ---------------- weight convert + transpose: dst[n*K+k] = bf16(src[k*N+n])
__global__ __launch_bounds__(256) void convT(const float* __restrict__ src,
                                             __bf16* __restrict__ dst, int K, int N) {
  __shared__ float tile[32][33];
  const int k0 = blockIdx.y * 32, n0 = blockIdx.x * 32;
  const int tx = threadIdx.x & 31, ty = threadIdx.x >> 5;  // 32 x 8
#pragma unroll
  for (int i = 0; i < 32; i += 8) tile[ty + i][tx] = src[(size_t)(k0 + ty + i) * N + n0 + tx];
  __syncthreads();
#pragma unroll
  for (int i = 0; i < 32; i += 8)
    dst[(size_t)(n0 + ty + i) * K + k0 + tx] = (__bf16)tile[tx][ty + i];
}

__global__ __launch_bounds__(256) void biascat_k(const float* __restrict__ bq,
                                                 const float* __restrict__ bk,
                                                 const float* __restrict__ bv,
                                                 float* __restrict__ bc) {
  int i = blockIdx.x * 256 + threadIdx.x;  // 1536 total
  bc[i] = (i < 512) ? bq[i] : (i < 1024) ? bk[i - 512] : bv[i - 1024];
}

__global__ __launch_bounds__(256) void zero_k(float* __restrict__ p, int n) {
  int i = blockIdx.x * 256 + threadIdx.x;
  if (i < n) p[i] = 0.f;
}

// ---------------- LayerNorm over D=512, one row per block (128 thr x float4)
__global__ __launch_bounds__(128) void ln_rows(const float* __restrict__ x,
                                               const float* __restrict__ g,
                                               const float* __restrict__ be,
                                               __bf16* __restrict__ out) {
  const int row = blockIdx.x, t = threadIdx.x;
  const float4 xv = reinterpret_cast<const float4*>(x + (size_t)row * 512)[t];
  float s = xv.x + xv.y + xv.z + xv.w;
  float s2 = xv.x * xv.x + xv.y * xv.y + xv.z * xv.z + xv.w * xv.w;
#pragma unroll
  for (int off = 32; off > 0; off >>= 1) { s += __shfl_down(s, off); s2 += __shfl_down(s2, off); }
  __shared__ float red[4];
  if ((t & 63) == 0) { red[(t >> 6) * 2] = s; red[(t >> 6) * 2 + 1] = s2; }
  __syncthreads();
  const float S = red[0] + red[2], S2 = red[1] + red[3];
  const float mean = S * (1.f / 512.f);
  const float var = S2 * (1.f / 512.f) - mean * mean;
  const float inv = rsqrtf(var + 1e-5f);
  const float4 gv = reinterpret_cast<const float4*>(g)[t];
  const float4 bv = reinterpret_cast<const float4*>(be)[t];
  b16x4 o;
  o[0] = (__bf16)((xv.x - mean) * inv * gv.x + bv.x);
  o[1] = (__bf16)((xv.y - mean) * inv * gv.y + bv.y);
  o[2] = (__bf16)((xv.z - mean) * inv * gv.z + bv.z);
  o[3] = (__bf16)((xv.w - mean) * inv * gv.w + bv.w);
  reinterpret_cast<b16x4*>(out + (size_t)row * 512)[t] = o;
}

// ---------------- x2 = x + sa0 + sa1 + bo (broadcast); d_out=x2; ln2=LN(x2)
__global__ __launch_bounds__(128) void x2ln2_k(const float* __restrict__ x,
                                               const float* __restrict__ sa0,
                                               const float* __restrict__ sa1,
                                               const float* __restrict__ bo,
                                               const float* __restrict__ g,
                                               const float* __restrict__ be,
                                               float* __restrict__ xout,
                                               __bf16* __restrict__ lnout) {
  const int row = blockIdx.x, t = threadIdx.x;
  const int l = row & (L_SEQ - 1);
  float4 xv = reinterpret_cast<const float4*>(x + (size_t)row * 512)[t];
  const float4 s0 = reinterpret_cast<const float4*>(sa0 + (size_t)l * 512)[t];
  const float4 s1 = reinterpret_cast<const float4*>(sa1 + (size_t)l * 512)[t];
  const float4 bb = reinterpret_cast<const float4*>(bo)[t];
  xv.x += s0.x + s1.x + bb.x; xv.y += s0.y + s1.y + bb.y;
  xv.z += s0.z + s1.z + bb.z; xv.w += s0.w + s1.w + bb.w;
  reinterpret_cast<float4*>(xout + (size_t)row * 512)[t] = xv;
  float s = xv.x + xv.y + xv.z + xv.w;
  float s2 = xv.x * xv.x + xv.y * xv.y + xv.z * xv.z + xv.w * xv.w;
#pragma unroll
  for (int off = 32; off > 0; off >>= 1) { s += __shfl_down(s, off); s2 += __shfl_down(s2, off); }
  __shared__ float red[4];
  if ((t & 63) == 0) { red[(t >> 6) * 2] = s; red[(t >> 6) * 2 + 1] = s2; }
  __syncthreads();
  const float S = red[0] + red[2], S2 = red[1] + red[3];
  const float mean = S * (1.f / 512.f);
  const float var = S2 * (1.f / 512.f) - mean * mean;
  const float inv = rsqrtf(var + 1e-5f);
  const float4 gv = reinterpret_cast<const float4*>(g)[t];
  const float4 bv = reinterpret_cast<const float4*>(be)[t];
  b16x4 o;
  o[0] = (__bf16)((xv.x - mean) * inv * gv.x + bv.x);
  o[1] = (__bf16)((xv.y - mean) * inv * gv.y + bv.y);
  o[2] = (__bf16)((xv.z - mean) * inv * gv.z + bv.z);
  o[3] = (__bf16)((xv.w - mean) * inv * gv.w + bv.w);
  reinterpret_cast<b16x4*>(lnout + (size_t)row * 512)[t] = o;
}

// ---------------- GEMM 128x128, BK=64, 32x32x16 MFMA, dbuf, 2 blocks/CU ----
// LDS (elems): buf b at b*16384: A region [0,8192), B region [8192,16384).
// Row layout: 128 rows x 64 elems (128B rows); chunk c (8 elems) of row r
// stored at slot c^(r&7). Staging source pre-swizzled (involution), dest
// linear: thread t, j=0..3 -> row (t>>3)+j*32, slot t&7.
// Fragment (32x32x16): A lane reads row l&31 (+m*32+wr*64), k-chunk
// c = ks*2+(l>>5) at slot c^(l&7). C/D: col=lane&31,
// row=(reg&3)+8*(reg>>2)+4*(lane>>5)  [verified m74/m101].
// EPI 0: QKV (+biascat, sigmoid q/k -> bf16 h0/h1 + column sums f1/f2; v->f0)
// EPI 1: SA  (val only -> f0, split-K via blockIdx.y when KSPL)
// EPI 2: GELU(+bias -> bf16 h0, stride N)
// EPI 3: OUT (f0[row,col] += acc + bias)
template <int EPI, int KSPL>
__global__ __launch_bounds__(256, 2) void gemm128(const __bf16* __restrict__ A,
                                                  const __bf16* __restrict__ Bt,
                                                  const int M, const int N, const int K,
                                                  const float* __restrict__ bias,
                                                  float* __restrict__ f0,
                                                  __bf16* __restrict__ h0,
                                                  __bf16* __restrict__ h1,
                                                  float* __restrict__ f1,
                                                  float* __restrict__ f2) {
  __shared__ alignas(16) __bf16 lds[32768];  // 64 KB

  if constexpr (KSPL) {
    const int z = blockIdx.y;
    A += (size_t)z * (K >> 1);
    Bt += (size_t)z * (K >> 1);
    f0 += (size_t)z * ((size_t)M * N);
  }
  const int nt = KSPL ? (K >> 7) : (K >> 6);   // K-tiles of 64

  // XCD-aware block swizzle (all x-grids are %8==0)
  const int nwg = gridDim.x;
  const int orig = blockIdx.x;
  const int cpx = nwg >> 3;
  const int wg = (orig & 7) * cpx + (orig >> 3);
  const int gx = N >> 7;
  const int bm = (wg / gx) << 7;
  const int bn = (wg % gx) << 7;

  const int t = threadIdx.x;
  const int w = t >> 6, lane = t & 63;
  const int wr = w >> 1, wc = w & 1;
  const int l31 = lane & 31, l5 = lane >> 5, l7 = lane & 7;

  // staging: thread t covers rows (t>>3)+j*32 (j=0..3), fixed slot t&7.
  // source chunk = slot ^ (row&7); row&7 == (t>>3)&7 (j*32 = 0 mod 8).
  const int sr = t >> 3;
  const int sc = (t & 7) ^ (sr & 7);
  const __bf16* Asrc = A + (size_t)(bm + sr) * K + sc * 8;
  const __bf16* Bsrc = Bt + (size_t)(bn + sr) * K + sc * 8;
  const int dst0 = t * 8;   // + j*2048 ; B region +8192; buf +16384

  f32x16 acc[2][2] = {};

  auto STG = [&](int s, int buf) {
    const int base = buf * 16384;
    const __bf16* ap = Asrc + (s << 6);
    const __bf16* bp = Bsrc + (s << 6);
#pragma unroll
    for (int j = 0; j < 4; j++) {
      gload16(ap + (size_t)(j << 5) * K, &lds[base + dst0 + (j << 11)]);
      gload16(bp + (size_t)(j << 5) * K, &lds[base + 8192 + dst0 + (j << 11)]);
    }
  };

  STG(0, 0);
  WAITV(0);
  BARF();

  int cur = 0;
  for (int s = 0; s < nt; s++) {
    if (s + 1 < nt) STG(s + 1, cur ^ 1);
    const int abase = cur * 16384 + (wr * 64 + l31) * 64;
    const int bbase = cur * 16384 + 8192 + (wc * 64 + l31) * 64;
#pragma unroll
    for (int ks = 0; ks < 4; ks++) {
      const int slot = ((ks * 2 + l5) ^ l7) * 8;
      const b16x8 a0 = *reinterpret_cast<const b16x8*>(&lds[abase + slot]);
      const b16x8 a1 = *reinterpret_cast<const b16x8*>(&lds[abase + 2048 + slot]);
      const b16x8 b0 = *reinterpret_cast<const b16x8*>(&lds[bbase + slot]);
      const b16x8 b1 = *reinterpret_cast<const b16x8*>(&lds[bbase + 2048 + slot]);
      acc[0][0] = __builtin_amdgcn_mfma_f32_32x32x16_bf16(a0, b0, acc[0][0], 0, 0, 0);
      acc[0][1] = __builtin_amdgcn_mfma_f32_32x32x16_bf16(a0, b1, acc[0][1], 0, 0, 0);
      acc[1][0] = __builtin_amdgcn_mfma_f32_32x32x16_bf16(a1, b0, acc[1][0], 0, 0, 0);
      acc[1][1] = __builtin_amdgcn_mfma_f32_32x32x16_bf16(a1, b1, acc[1][1], 0, 0, 0);
    }
    WAITV(0);
    BARF();
    cur ^= 1;
  }

  // epilogue: C/D col=lane&31, row=(j&3)+8*(j>>2)+4*l5
  if constexpr (EPI == 0) {
    const int which = bn >> 9;  // 0=q, 1=k, 2=v (uniform per block)
    float cs[2] = {0.f, 0.f};
#pragma unroll
    for (int m = 0; m < 2; m++) {
#pragma unroll
      for (int n = 0; n < 2; n++) {
        const int col = bn + wc * 64 + n * 32 + l31;
        const int c2 = col & 511;
#pragma unroll
        for (int j = 0; j < 16; j++) {
          const int row = bm + wr * 64 + m * 32 + (j & 3) + 8 * (j >> 2) + 4 * l5;
          float val = acc[m][n][j] + bias[col];
          if (which < 2) {
            val = sigmoidf_(val);
            cs[n] += val;
            ((which == 0) ? h0 : h1)[(size_t)row * 512 + c2] = (__bf16)val;
          } else {
            f0[(size_t)row * 512 + c2] = val;
          }
        }
      }
    }
    if (which < 2) {
      float* sums = (which == 0) ? f1 : f2;
#pragma unroll
      for (int n = 0; n < 2; n++) {
        float s = cs[n];
        s += __shfl_xor(s, 32);
        if (l5 == 0) atomicAdd(&sums[(bn & 511) + wc * 64 + n * 32 + l31], s);
      }
    }
  } else {
#pragma unroll
    for (int m = 0; m < 2; m++) {
#pragma unroll
      for (int n = 0; n < 2; n++) {
        const int col = bn + wc * 64 + n * 32 + l31;
#pragma unroll
        for (int j = 0; j < 16; j++) {
          const int row = bm + wr * 64 + m * 32 + (j & 3) + 8 * (j >> 2) + 4 * l5;
          float val = acc[m][n][j];
          if constexpr (EPI == 1) {
            f0[(size_t)row * N + col] = val;
          } else if constexpr (EPI == 2) {
            const float xg = val + bias[col];
            const float gel = 0.5f * xg * (1.f + erff(xg * 0.70710678118f));
            h0[(size_t)row * N + col] = (__bf16)gel;
          } else {
            const size_t idx = (size_t)row * N + col;
            f0[idx] = f0[idx] + val + bias[col];
          }
        }
      }
    }
  }
}

// ---------------- attention pass 1: si/so per (h,l); qsi/kso block partials --
__global__ __launch_bounds__(256) void attn_pass1(const __bf16* __restrict__ q,
                                                  const __bf16* __restrict__ k,
                                                  const float* __restrict__ qsum,
                                                  const float* __restrict__ ksum,
                                                  float* __restrict__ si_out,
                                                  float* __restrict__ qkpart) {
  __shared__ float lsQ[512], lsK[512];
  const int t = threadIdx.x, lane = t & 63, wv = t >> 6;
  const int c0 = lane * 8;
  lsQ[t] = 0.f; lsQ[t + 256] = 0.f;
  lsK[t] = 0.f; lsK[t + 256] = 0.f;
  __syncthreads();
  float qs[8], ks[8];
#pragma unroll
  for (int j = 0; j < 8; j++) {
    qs[j] = qsum[c0 + j] + EPSF;
    ks[j] = ksum[c0 + j] + EPSF;
  }
  const int h = lane >> 3;
  float qacc[8] = {}, kacc[8] = {};
#pragma unroll 1
  for (int i = 0; i < 8; i++) {
    const int l = blockIdx.x * 32 + wv * 8 + i;
    const b16x8 q8 = *reinterpret_cast<const b16x8*>(q + (size_t)l * 512 + c0);
    const b16x8 k8 = *reinterpret_cast<const b16x8*>(k + (size_t)l * 512 + c0);
    float qf[8], kf[8];
    float p1 = 0.f, p2 = 0.f;
#pragma unroll
    for (int j = 0; j < 8; j++) {
      qf[j] = (float)q8[j]; kf[j] = (float)k8[j];
      p1 += (qf[j] + EPSF) * ks[j];
      p2 += (kf[j] + EPSF) * qs[j];
    }
    p1 += __shfl_xor(p1, 1); p2 += __shfl_xor(p2, 1);
    p1 += __shfl_xor(p1, 2); p2 += __shfl_xor(p2, 2);
    p1 += __shfl_xor(p1, 4); p2 += __shfl_xor(p2, 4);
    const float siv = 1.f / p1, sov = 1.f / p2;
    if ((lane & 7) == 0) si_out[h * L_SEQ + l] = siv;
#pragma unroll
    for (int j = 0; j < 8; j++) { qacc[j] += qf[j] * siv; kacc[j] += kf[j] * sov; }
  }
#pragma unroll
  for (int j = 0; j < 8; j++) {
    atomicAdd(&lsQ[c0 + j], qacc[j]);   // LDS atomics: 4 waves, cheap
    atomicAdd(&lsK[c0 + j], kacc[j]);
  }
  __syncthreads();
  float* qp = qkpart + (size_t)blockIdx.x * 1024;
  qp[t] = lsQ[t];
  qp[t + 256] = lsQ[t + 256];
  qp[t + 512] = lsK[t];
  qp[t + 768] = lsK[t + 256];
}

// reduce 512 block-partials -> qsi[0..511] | kso[0..511] (contiguous output)
__global__ __launch_bounds__(256) void reduce_qk(const float* __restrict__ qkpart,
                                                 float* __restrict__ outv) {
  const int i = blockIdx.x * 256 + threadIdx.x;  // 0..1023
  float s = 0.f;
#pragma unroll 4
  for (int b = 0; b < 512; b++) s += qkpart[(size_t)b * 1024 + i];
  outv[i] = s;
}

// ---------------- kv partials: compE inline; no atomics -----------------------
__global__ __launch_bounds__(256) void kv_part(const __bf16* __restrict__ k,
                                               const float* __restrict__ v,
                                               const float* __restrict__ qsi,
                                               float* __restrict__ kvpart,
                                               float* __restrict__ separt) {
  const int h = blockIdx.y, bx = blockIdx.x, t = threadIdx.x;
  __shared__ float lsK[64 * 68];
  __shared__ float lsV[64 * 68];
  __shared__ float lsRed[256];
  const int r = t >> 2, cq = (t & 3) * 16;
  float qv[16];
#pragma unroll
  for (int j = 0; j < 16; j++) qv[j] = qsi[h * 64 + cq + j] + EPSF;
  const int d = t & 63, mg = t >> 6;
  f32x4 acc4[4] = {};
  float seloc = 0.f;
#pragma unroll 1
  for (int sc = 0; sc < 4; sc++) {
    const int l = bx * 256 + sc * 64 + r;
    __syncthreads();
    const b16x8 k8a = *reinterpret_cast<const b16x8*>(k + (size_t)l * 512 + h * 64 + cq);
    const b16x8 k8b = *reinterpret_cast<const b16x8*>(k + (size_t)l * 512 + h * 64 + cq + 8);
    f32x4 v4[4];
#pragma unroll
    for (int jj = 0; jj < 4; jj++)
      v4[jj] = *reinterpret_cast<const f32x4*>(v + (size_t)l * 512 + h * 64 + cq + jj * 4);
    float kf[16];
#pragma unroll
    for (int j = 0; j < 8; j++) { kf[j] = (float)k8a[j]; kf[8 + j] = (float)k8b[j]; }
    float p = 0.f;
#pragma unroll
    for (int j = 0; j < 16; j++) p += (kf[j] + EPSF) * qv[j];
    p += __shfl_xor(p, 1);
    p += __shfl_xor(p, 2);
    p = fminf(fmaxf(p, -1.f), 1.f);
    const float ce = __expf(p);
    if ((t & 3) == 0) seloc += ce;
#pragma unroll
    for (int j = 0; j < 16; j++) lsK[r * 68 + cq + j] = kf[j];
#pragma unroll
    for (int jj = 0; jj < 4; jj++)
      *reinterpret_cast<f32x4*>(&lsV[r * 68 + cq + jj * 4]) = v4[jj] * ce;
    __syncthreads();
    for (int rr = 0; rr < 64; rr++) {
      const float kd = lsK[rr * 68 + d];
      const f32x4* lv = reinterpret_cast<const f32x4*>(&lsV[rr * 68 + mg * 16]);
#pragma unroll
      for (int jj = 0; jj < 4; jj++) acc4[jj] += lv[jj] * kd;
    }
  }
  float* kp = kvpart + ((size_t)h * 64 + bx) * 4096;
#pragma unroll
  for (int jj = 0; jj < 4; jj++)
    *reinterpret_cast<f32x4*>(&kp[d * 64 + mg * 16 + jj * 4]) = acc4[jj];
  lsRed[t] = ((t & 3) == 0) ? seloc : 0.f;
  __syncthreads();
  for (int s2 = 128; s2 > 0; s2 >>= 1) {
    if (t < s2) lsRed[t] += lsRed[t + s2];
    __syncthreads();
  }
  if (t == 0) separt[h * 64 + bx] = lsRed[0];
}

// sum 64 kv partial slabs; also reduce separt -> sumexp[h]
__global__ __launch_bounds__(256) void kv_reduce(const float* __restrict__ kvpart,
                                                 const float* __restrict__ separt,
                                                 float* __restrict__ kvout,
                                                 float* __restrict__ sumexp) {
  const int h = blockIdx.y, t = threadIdx.x;
  const int i = blockIdx.x * 256 + t;
  float s = 0.f;
#pragma unroll 4
  for (int b = 0; b < 64; b++) s += kvpart[((size_t)h * 64 + b) * 4096 + i];
  kvout[h * 4096 + i] = s;
  if (blockIdx.x == 0 && t < 64) {
    float e = separt[h * 64 + t];
#pragma unroll
    for (int off2 = 32; off2 > 0; off2 >>= 1) e += __shfl_down(e, off2);
    if (t == 0) sumexp[h] = e;
  }
}

// ---------------- o: sal inline; o = (q@kv_raw) * si * sal * (L/sumexp) ------
__global__ __launch_bounds__(256) void o_kernel(const __bf16* __restrict__ q,
                                                const float* __restrict__ kvin,
                                                const float* __restrict__ si,
                                                const float* __restrict__ kso,
                                                const float* __restrict__ sumexp,
                                                __bf16* __restrict__ o) {
  const int h = blockIdx.y;
  const int l0 = blockIdx.x * 32;
  const int t = threadIdx.x;
  __shared__ float lsKV[64 * 64];
  __shared__ float lsQ[32 * 65];
  __shared__ float lsF[32];
  const float Sfac = (float)L_SEQ / sumexp[h];
#pragma unroll
  for (int j = 0; j < 16; j++) lsKV[t + j * 256] = kvin[h * 4096 + t + j * 256];
  const int r = t >> 3, c8 = (t & 7) * 8;
  float ksov[8];
#pragma unroll
  for (int j = 0; j < 8; j++) ksov[j] = kso[h * 64 + c8 + j] + EPSF;
  const b16x8 q8 = *reinterpret_cast<const b16x8*>(q + (size_t)(l0 + r) * 512 + h * 64 + c8);
  float p = 0.f;
#pragma unroll
  for (int j = 0; j < 8; j++) {
    const float qf = (float)q8[j];
    lsQ[r * 65 + c8 + j] = qf;
    p += (qf + EPSF) * ksov[j];
  }
  p += __shfl_xor(p, 1);
  p += __shfl_xor(p, 2);
  p += __shfl_xor(p, 4);
  if ((t & 7) == 0) lsF[r] = sigmoidf_(p) * si[h * L_SEQ + l0 + r] * Sfac;
  __syncthreads();
  const int m = t & 63, rg = t >> 6;
#pragma unroll 1
  for (int i = 0; i < 8; i++) {
    const int rr = rg + i * 4;
    float a = 0.f;
#pragma unroll
    for (int dd = 0; dd < 64; dd++) a += lsQ[rr * 65 + dd] * lsKV[dd * 64 + m];
    o[(size_t)(l0 + rr) * 512 + h * 64 + m] = (__bf16)(a * lsF[rr]);
  }
}

// ---------------------------------------------------------------------------
extern "C" void kernel_launch(void* const* d_in, const int* in_sizes, int n_in,
                              void* d_out, int out_size, void* d_ws, size_t ws_size,
                              hipStream_t stream) {
  const float* x  = (const float*)d_in[0];
  const float* Wq = (const float*)d_in[1];
  const float* bq = (const float*)d_in[2];
  const float* Wk = (const float*)d_in[3];
  const float* bk = (const float*)d_in[4];
  const float* Wv = (const float*)d_in[5];
  const float* bv = (const float*)d_in[6];
  const float* Wo = (const float*)d_in[7];
  const float* bo = (const float*)d_in[8];
  const float* W1 = (const float*)d_in[9];
  const float* b1 = (const float*)d_in[10];
  const float* W2 = (const float*)d_in[11];
  const float* b2 = (const float*)d_in[12];
  const float* g1 = (const float*)d_in[13];
  const float* be1 = (const float*)d_in[14];
  const float* g2 = (const float*)d_in[15];
  const float* be2 = (const float*)d_in[16];
  float* out = (float*)d_out;

  char* ws = (char*)d_ws;
  size_t off = 0;
  auto alloc = [&](size_t bytes) -> char* {
    char* p = ws + off;
    off += (bytes + 255) & ~(size_t)255;
    return p;
  };

  // Region A (134.2 MB), time-multiplexed:
  //   phase 1 (attention): ln1 | qb16 | kb16 | vb | ob
  //   phase 2 (Wo+x2ln2):  sa (2x33.5 MB at offset 0; ob at 83.9 MB still live)
  //   phase 3 (MLP):       act (full region)
  char* regA = alloc(134217728);
  __bf16* ln1  = (__bf16*)regA;                      // 16.78 MB
  __bf16* qb16 = (__bf16*)(regA + 16777216);         // 16.78 MB
  __bf16* kb16 = (__bf16*)(regA + 33554432);         // 16.78 MB
  float*  vb   = (float*)(regA + 50331648);          // 33.55 MB
  __bf16* ob   = (__bf16*)(regA + 83886080);         // 16.78 MB
  float*  sa   = (float*)regA;                       // 67.1 MB (2 splits)
  __bf16* act  = (__bf16*)regA;                      // 134.2 MB

  __bf16* ln2 = (__bf16*)alloc((size_t)32768 * 512 * 2);
  __bf16* Wqkvt = (__bf16*)alloc((size_t)1536 * 512 * 2);
  __bf16* Wot = (__bf16*)alloc((size_t)512 * 512 * 2);
  __bf16* W1t = (__bf16*)alloc((size_t)2048 * 512 * 2);
  __bf16* W2t = (__bf16*)alloc((size_t)512 * 2048 * 2);
  float* biascat = (float*)alloc(1536 * 4);
  float* si = (float*)alloc((size_t)8 * L_SEQ * 4);
  float* stats = (float*)alloc(34880 * 4);  // qsum|ksum|qsi|kso|sumexp|kv
  float* qsum = stats;
  float* ksum = stats + 512;
  float* qsi = stats + 1024;       // qsi[512] | kso[512] contiguous
  float* kso = stats + 1536;
  float* sumexp = stats + 2048;
  float* kvbuf = stats + 2112;
  float* kvpart = (float*)alloc((size_t)8 * 64 * 4096 * 4);  // 8.39 MB
  float* separt = (float*)alloc(512 * 4);
  float* qkpart = (float*)alloc((size_t)512 * 1024 * 4);     // 2.10 MB

  // weights -> bf16 transposed
  convT<<<dim3(16, 16), 256, 0, stream>>>(Wq, Wqkvt, 512, 512);
  convT<<<dim3(16, 16), 256, 0, stream>>>(Wk, Wqkvt + (size_t)512 * 512, 512, 512);
  convT<<<dim3(16, 16), 256, 0, stream>>>(Wv, Wqkvt + (size_t)1024 * 512, 512, 512);
  convT<<<dim3(16, 16), 256, 0, stream>>>(Wo, Wot, 512, 512);
  convT<<<dim3(64, 16), 256, 0, stream>>>(W1, W1t, 512, 2048);
  convT<<<dim3(16, 64), 256, 0, stream>>>(W2, W2t, 2048, 512);
  biascat_k<<<6, 256, 0, stream>>>(bq, bk, bv, biascat);
  zero_k<<<(2112 + 255) / 256, 256, 0, stream>>>(stats, 2112);  // qsum..sumexp

  // LN1 (batch 0 only) -> QKV GEMM (sigmoid q,k -> bf16; colsums fused)
  ln_rows<<<L_SEQ, 128, 0, stream>>>(x, g1, be1, ln1);
  gemm128<0, 0><<<1536, 256, 0, stream>>>(ln1, Wqkvt, L_SEQ, 1536, 512,
                                          biascat, vb, qb16, kb16, qsum, ksum);

  // fused attention chain, slab-reduced (no contended atomics)
  attn_pass1<<<512, 256, 0, stream>>>(qb16, kb16, qsum, ksum, si, qkpart);
  reduce_qk<<<4, 256, 0, stream>>>(qkpart, qsi);
  kv_part<<<dim3(64, 8), 256, 0, stream>>>(kb16, vb, qsi, kvpart, separt);
  kv_reduce<<<dim3(16, 8), 256, 0, stream>>>(kvpart, separt, kvbuf, sumexp);
  o_kernel<<<dim3(L_SEQ / 32, 8), 256, 0, stream>>>(qb16, kvbuf, si, kso, sumexp, ob);

  // sa = o @ Wo (split-K x2, bias folded into x2ln2)
  gemm128<1, 1><<<dim3(512, 2), 256, 0, stream>>>(ob, Wot, L_SEQ, 512, 512,
                                                  nullptr, sa, nullptr, nullptr,
                                                  nullptr, nullptr);

  // x2 = x + sa0 + sa1 + bo -> d_out; ln2 = LN(x2)
  x2ln2_k<<<2 * L_SEQ, 128, 0, stream>>>(x, sa, sa + (size_t)L_SEQ * 512, bo,
                                         g2, be2, out, ln2);

  // MLP: act = gelu(ln2 @ W1 + b1);  d_out += act @ W2 + b2
  gemm128<2, 0><<<4096, 256, 0, stream>>>(ln2, W1t, 2 * L_SEQ, 2048, 512,
                                          b1, nullptr, act, nullptr, nullptr, nullptr);
  gemm128<3, 0><<<1024, 256, 0, stream>>>(act, W2t, 2 * L_SEQ, 512, 2048,
                                          b2, out, nullptr, nullptr, nullptr, nullptr);
}

// Round 11
// 534.784 us; speedup vs baseline: 1.0712x; 1.0712x over previous
//
#include <hip/hip_runtime.h>
#include <hip/hip_bf16.h>
#include <cstdint>
#include <cstddef>

// ---------------------------------------------------------------------------
// FlowformerLayer: LN1 -> flow-attention(batch0) -> +res -> LN2 -> MLP -> +res
// W1/W2: gemm256z — 256x256, BK=64, 8 waves, 4-phase zigzag window, unit-
//   aligned staging (A-unit(mh)=rows wm*128+mh*64+[0,64); B-unit(u)=bit6
//   halves), 1 unit staged/phase into the non-read buffer (no intra-window
//   hazard BY CONSTRUCTION), counted WAITV(4) mid / WAITV(2) end.
//   Ledger (steady): mid outstanding = A-u1(t)+A-u0(t+1)+B-u0(t+1)=6 ->
//   WAITV(4) lands A-u1(t) (needed q11/q10). End outstanding = 4 units of
//   t+1 = 8 -> WAITV(2) lands A-u0/B-u0/B-u1(t+1) (needed q00'), leaves
//   A-u1(t+1) riding to next mid-wait. Tail: mid -> WAITV(0) when no stages.
// QKV/Wo: R6 gemm128 (best measured; 4 blocks/CU). v stored bf16.
// Attention: 3 passes over bf16 q/k/v, slab-reduced (no contended atomics).
// ---------------------------------------------------------------------------

#define L_SEQ 16384
#define EPSF 1e-6f

typedef __bf16 b16x8 __attribute__((ext_vector_type(8)));
typedef __bf16 b16x4 __attribute__((ext_vector_type(4)));
typedef float  f32x4 __attribute__((ext_vector_type(4)));

#define FENCE() asm volatile("" ::: "memory")
#define BARF()  { FENCE(); __builtin_amdgcn_s_barrier(); FENCE(); }
#define WAITV(n) asm volatile("s_waitcnt vmcnt(" #n ")" ::: "memory")

__device__ __forceinline__ void gload16(const void* g, void* l) {
  __builtin_amdgcn_global_load_lds((const __attribute__((address_space(1))) void*)g,
                                   (__attribute__((address_space(3))) void*)l, 16, 0, 0);
}

__device__ __forceinline__ float sigmoidf_(float x) { return 1.f / (1.f + __expf(-x)); }

// ---------------- weight convert + transpose: dst[n*K+k] = bf16(src[k*N+n])
__global__ __launch_bounds__(256) void convT(const float* __restrict__ src,
                                             __bf16* __restrict__ dst, int K, int N) {
  __shared__ float tile[32][33];
  const int k0 = blockIdx.y * 32, n0 = blockIdx.x * 32;
  const int tx = threadIdx.x & 31, ty = threadIdx.x >> 5;
#pragma unroll
  for (int i = 0; i < 32; i += 8) tile[ty + i][tx] = src[(size_t)(k0 + ty + i) * N + n0 + tx];
  __syncthreads();
#pragma unroll
  for (int i = 0; i < 32; i += 8)
    dst[(size_t)(n0 + ty + i) * K + k0 + tx] = (__bf16)tile[tx][ty + i];
}

__global__ __launch_bounds__(256) void biascat_k(const float* __restrict__ bq,
                                                 const float* __restrict__ bk,
                                                 const float* __restrict__ bv,
                                                 float* __restrict__ bc) {
  int i = blockIdx.x * 256 + threadIdx.x;
  bc[i] = (i < 512) ? bq[i] : (i < 1024) ? bk[i - 512] : bv[i - 1024];
}

__global__ __launch_bounds__(256) void zero_k(float* __restrict__ p, int n) {
  int i = blockIdx.x * 256 + threadIdx.x;
  if (i < n) p[i] = 0.f;
}

// ---------------- LayerNorm over D=512, one row per block
__global__ __launch_bounds__(128) void ln_rows(const float* __restrict__ x,
                                               const float* __restrict__ g,
                                               const float* __restrict__ be,
                                               __bf16* __restrict__ out) {
  const int row = blockIdx.x, t = threadIdx.x;
  const float4 xv = reinterpret_cast<const float4*>(x + (size_t)row * 512)[t];
  float s = xv.x + xv.y + xv.z + xv.w;
  float s2 = xv.x * xv.x + xv.y * xv.y + xv.z * xv.z + xv.w * xv.w;
#pragma unroll
  for (int off = 32; off > 0; off >>= 1) { s += __shfl_down(s, off); s2 += __shfl_down(s2, off); }
  __shared__ float red[4];
  if ((t & 63) == 0) { red[(t >> 6) * 2] = s; red[(t >> 6) * 2 + 1] = s2; }
  __syncthreads();
  const float S = red[0] + red[2], S2 = red[1] + red[3];
  const float mean = S * (1.f / 512.f);
  const float var = S2 * (1.f / 512.f) - mean * mean;
  const float inv = rsqrtf(var + 1e-5f);
  const float4 gv = reinterpret_cast<const float4*>(g)[t];
  const float4 bv = reinterpret_cast<const float4*>(be)[t];
  b16x4 o;
  o[0] = (__bf16)((xv.x - mean) * inv * gv.x + bv.x);
  o[1] = (__bf16)((xv.y - mean) * inv * gv.y + bv.y);
  o[2] = (__bf16)((xv.z - mean) * inv * gv.z + bv.z);
  o[3] = (__bf16)((xv.w - mean) * inv * gv.w + bv.w);
  reinterpret_cast<b16x4*>(out + (size_t)row * 512)[t] = o;
}

// ---------------- x2 = x + sa0 + sa1 + bo; d_out=x2; ln2=LN(x2)
__global__ __launch_bounds__(128) void x2ln2_k(const float* __restrict__ x,
                                               const float* __restrict__ sa0,
                                               const float* __restrict__ sa1,
                                               const float* __restrict__ bo,
                                               const float* __restrict__ g,
                                               const float* __restrict__ be,
                                               float* __restrict__ xout,
                                               __bf16* __restrict__ lnout) {
  const int row = blockIdx.x, t = threadIdx.x;
  const int l = row & (L_SEQ - 1);
  float4 xv = reinterpret_cast<const float4*>(x + (size_t)row * 512)[t];
  const float4 s0 = reinterpret_cast<const float4*>(sa0 + (size_t)l * 512)[t];
  const float4 s1 = reinterpret_cast<const float4*>(sa1 + (size_t)l * 512)[t];
  const float4 bb = reinterpret_cast<const float4*>(bo)[t];
  xv.x += s0.x + s1.x + bb.x; xv.y += s0.y + s1.y + bb.y;
  xv.z += s0.z + s1.z + bb.z; xv.w += s0.w + s1.w + bb.w;
  reinterpret_cast<float4*>(xout + (size_t)row * 512)[t] = xv;
  float s = xv.x + xv.y + xv.z + xv.w;
  float s2 = xv.x * xv.x + xv.y * xv.y + xv.z * xv.z + xv.w * xv.w;
#pragma unroll
  for (int off = 32; off > 0; off >>= 1) { s += __shfl_down(s, off); s2 += __shfl_down(s2, off); }
  __shared__ float red[4];
  if ((t & 63) == 0) { red[(t >> 6) * 2] = s; red[(t >> 6) * 2 + 1] = s2; }
  __syncthreads();
  const float S = red[0] + red[2], S2 = red[1] + red[3];
  const float mean = S * (1.f / 512.f);
  const float var = S2 * (1.f / 512.f) - mean * mean;
  const float inv = rsqrtf(var + 1e-5f);
  const float4 gv = reinterpret_cast<const float4*>(g)[t];
  const float4 bv = reinterpret_cast<const float4*>(be)[t];
  b16x4 o;
  o[0] = (__bf16)((xv.x - mean) * inv * gv.x + bv.x);
  o[1] = (__bf16)((xv.y - mean) * inv * gv.y + bv.y);
  o[2] = (__bf16)((xv.z - mean) * inv * gv.z + bv.z);
  o[3] = (__bf16)((xv.w - mean) * inv * gv.w + bv.w);
  reinterpret_cast<b16x4*>(lnout + (size_t)row * 512)[t] = o;
}

// ---------------- gemm128 (R6 config): QKV + Wo -----------------------------
template <int EPI, int KSPL>
__global__ __launch_bounds__(256, 4) void gemm128(const __bf16* __restrict__ A,
                                                  const __bf16* __restrict__ Bt,
                                                  const int M, const int N, const int K,
                                                  const float* __restrict__ bias,
                                                  float* __restrict__ f0,
                                                  __bf16* __restrict__ h0,
                                                  __bf16* __restrict__ h1,
                                                  float* __restrict__ f1,
                                                  float* __restrict__ f2) {
  __shared__ alignas(16) __bf16 lds[16384];  // 32 KB

  if constexpr (KSPL) {
    const int z = blockIdx.y;
    A += (size_t)z * (K >> 1);
    Bt += (size_t)z * (K >> 1);
    f0 += (size_t)z * ((size_t)M * N);
  }
  const int nt = KSPL ? (K >> 6) : (K >> 5);

  const int nwg = gridDim.x;
  const int orig = blockIdx.x;
  const int cpx = nwg >> 3;
  const int wg = (orig & 7) * cpx + (orig >> 3);
  const int gx = N >> 7;
  const int bm = (wg / gx) << 7;
  const int bn = (wg % gx) << 7;

  const int t = threadIdx.x;
  const int w = t >> 6, lane = t & 63;
  const int wr = w >> 1, wc = w & 1;
  const int fr = lane & 15;
  const int kb = lane >> 4;

  const __bf16* As = A + (size_t)(bm + (t >> 2)) * K + (t & 3) * 8;
  const __bf16* Bs = Bt + (size_t)(bn + (t >> 2)) * K + (t & 3) * 8;

  f32x4 acc[4][4] = {};

  auto STG = [&](int s) {
    const int sel = (s & 1) * 4096;
    const __bf16* ap = As + (s << 5);
    const __bf16* bp = Bs + (s << 5);
    gload16(ap, &lds[sel + t * 8]);
    gload16(ap + (size_t)64 * K, &lds[sel + 2048 + t * 8]);
    gload16(bp, &lds[8192 + sel + t * 8]);
    gload16(bp + (size_t)64 * K, &lds[8192 + sel + 2048 + t * 8]);
  };

  STG(0);
  WAITV(0);
  BARF();

  for (int s = 0; s < nt; s++) {
    if (s + 1 < nt) STG(s + 1);
    const int ab = (s & 1) * 4096 + (wr * 64 + fr) * 32 + kb * 8;
    const int bb2 = 8192 + (s & 1) * 4096 + (wc * 64 + fr) * 32 + kb * 8;
    b16x8 av[4], bv[4];
#pragma unroll
    for (int m = 0; m < 4; m++)
      av[m] = *reinterpret_cast<const b16x8*>(&lds[ab + m * 512]);
#pragma unroll
    for (int n = 0; n < 4; n++)
      bv[n] = *reinterpret_cast<const b16x8*>(&lds[bb2 + n * 512]);
#pragma unroll
    for (int m = 0; m < 4; m++)
#pragma unroll
      for (int n = 0; n < 4; n++)
        acc[m][n] = __builtin_amdgcn_mfma_f32_16x16x32_bf16(av[m], bv[n], acc[m][n], 0, 0, 0);
    WAITV(0);
    BARF();
  }

  const int r0 = kb * 4;
  const int cc = fr;
  if constexpr (EPI == 0) {
    const int which = bn >> 9;  // 0=q, 1=k, 2=v
    float cs[4] = {0.f, 0.f, 0.f, 0.f};
#pragma unroll
    for (int m = 0; m < 4; m++) {
#pragma unroll
      for (int n = 0; n < 4; n++) {
        const int col = bn + wc * 64 + n * 16 + cc;
        const int c2 = col & 511;
#pragma unroll
        for (int r = 0; r < 4; r++) {
          const int row = bm + wr * 64 + m * 16 + r0 + r;
          float val = acc[m][n][r] + bias[col];
          if (which < 2) {
            val = sigmoidf_(val);
            cs[n] += val;
            ((which == 0) ? h0 : h1)[(size_t)row * 512 + c2] = (__bf16)val;
          } else {
            ((__bf16*)f0)[(size_t)row * 512 + c2] = (__bf16)val;  // v as bf16
          }
        }
      }
    }
    if (which < 2) {
      float* sums = (which == 0) ? f1 : f2;
#pragma unroll
      for (int n = 0; n < 4; n++) {
        float s = cs[n];
        s += __shfl_xor(s, 16);
        s += __shfl_xor(s, 32);
        if (kb == 0) atomicAdd(&sums[(bn & 511) + wc * 64 + n * 16 + cc], s);
      }
    }
  } else {
#pragma unroll
    for (int m = 0; m < 4; m++) {
#pragma unroll
      for (int n = 0; n < 4; n++) {
        const int col = bn + wc * 64 + n * 16 + cc;
#pragma unroll
        for (int r = 0; r < 4; r++) {
          const int row = bm + wr * 64 + m * 16 + r0 + r;
          f0[(size_t)row * N + col] = acc[m][n][r];
        }
      }
    }
  }
}

// ---------------- gemm256z: 256x256, 4-phase zigzag, counted vmcnt ----------
// LDS bases (elems): Abuf0=0, Abuf1=16384, Bbuf0=32768, Bbuf1=49152.
// Tile layout per region: 256 rows x 64 elems, slot swizzle c^(r&7)
// (R2-verified pair: linear dest + pre-swizzled source + swizzled read).
// EPI 2: GELU(+bias -> bf16 h0); EPI 3: f0 += acc + bias.
template <int EPI>
__global__ __launch_bounds__(512) void gemm256z(const __bf16* __restrict__ A,
                                                const __bf16* __restrict__ Bt,
                                                const int M, const int N, const int K,
                                                const float* __restrict__ bias,
                                                float* __restrict__ f0,
                                                __bf16* __restrict__ h0) {
  __shared__ alignas(16) __bf16 lds[65536];  // 128 KB

  const int nt = K >> 6;

  const int nwg = gridDim.x;
  const int orig = blockIdx.x;
  const int cpx = nwg >> 3;
  const int wg = (orig & 7) * cpx + (orig >> 3);
  const int gx = N >> 8;
  const int bm = (wg / gx) << 8;
  const int bn = (wg % gx) << 8;

  const int t = threadIdx.x;
  const int w = t >> 6, lane = t & 63;
  const int wm = w >> 2, wn = w & 3;
  const int fr = lane & 15;
  const int kb = lane >> 4;
  const int l7 = lane & 7;

  // staging: thread t covers row rb + (t>>3), slot t&7; source chunk
  // pre-swizzled: sc = (t&7) ^ ((t>>3)&7). dest elem = dbase + rb*64 + t*8.
  const int sr = t >> 3;
  const int sc = (t & 7) ^ (sr & 7);
  const __bf16* As = A + (size_t)(bm + sr) * K + sc * 8;
  const __bf16* Bs = Bt + (size_t)(bn + sr) * K + sc * 8;
  const int dst0 = t * 8;

  f32x4 acc[8][4] = {};
  b16x8 av[8], bv[4];

  // stage one unit (2 rowblocks of 64 rows) of K-tile s
  auto STGU = [&](const __bf16* src, int s, int rb1, int rb2, int dbase) {
    const __bf16* p = src + (s << 6);
    gload16(p + (size_t)rb1 * K, &lds[dbase + rb1 * 64 + dst0]);
    gload16(p + (size_t)rb2 * K, &lds[dbase + rb2 * 64 + dst0]);
  };

  auto RDA = [&](int mh, int abase) {
#pragma unroll
    for (int ml = 0; ml < 4; ml++)
#pragma unroll
      for (int ks = 0; ks < 2; ks++) {
        const int row = wm * 128 + mh * 64 + ml * 16 + fr;
        const int sw = (((ks << 2) | kb) ^ l7) << 3;
        av[ml * 2 + ks] = *reinterpret_cast<const b16x8*>(&lds[abase + row * 64 + sw]);
      }
  };
  auto RDB = [&](int nh, int bbase) {
#pragma unroll
    for (int nl = 0; nl < 2; nl++)
#pragma unroll
      for (int ks = 0; ks < 2; ks++) {
        const int row = wn * 64 + nh * 32 + nl * 16 + fr;
        const int sw = (((ks << 2) | kb) ^ l7) << 3;
        bv[nl * 2 + ks] = *reinterpret_cast<const b16x8*>(&lds[bbase + row * 64 + sw]);
      }
  };
  auto MMQ = [&](int mh, int nh) {
    __builtin_amdgcn_s_setprio(1);
#pragma unroll
    for (int ml = 0; ml < 4; ml++)
#pragma unroll
      for (int nl = 0; nl < 2; nl++)
#pragma unroll
        for (int ks = 0; ks < 2; ks++)
          acc[mh * 4 + ml][nh * 2 + nl] = __builtin_amdgcn_mfma_f32_16x16x32_bf16(
              av[ml * 2 + ks], bv[nl * 2 + ks], acc[mh * 4 + ml][nh * 2 + nl], 0, 0, 0);
    __builtin_amdgcn_s_setprio(0);
  };

  // prologue: tile0 all units (8 loads) + tile1 A-u0, B-u0 (4 loads)
  STGU(As, 0, 0, 128, 0);        // A-u0(0)
  STGU(As, 0, 64, 192, 0);       // A-u1(0)
  STGU(Bs, 0, 0, 128, 32768);    // B-u0(0)
  STGU(Bs, 0, 64, 192, 32768);   // B-u1(0)
  STGU(As, 1, 0, 128, 16384);    // A-u0(1)
  STGU(Bs, 1, 0, 128, 49152);    // B-u0(1)
  WAITV(4);   // tile0's 8 loads landed; tile1's 4 in flight
  BARF();

  for (int s = 0; s < nt; s++) {
    const int cur = s & 1;
    const int abase = cur ? 16384 : 0;
    const int bbase = cur ? 49152 : 32768;
    const int aoth = cur ? 0 : 16384;
    const int both = cur ? 32768 : 49152;
    const bool more = (s + 1 < nt);
    const bool st01 = more && (s > 0);  // window 0: A-u0/B-u0(1) prologue-staged

    // q00: quad(m0-3, n0-1); stage A-u0(s+1)
    RDA(0, abase); RDB(0, bbase);
    MMQ(0, 0);
    if (st01) STGU(As, s + 1, 0, 128, aoth);
    // q01: quad(m0-3, n2-3); stage B-u0(s+1)
    RDB(1, bbase);
    MMQ(0, 1);
    if (st01) STGU(Bs, s + 1, 0, 128, both);
    // mid-wait: land A-u1(s) (the deep rider) before q11/q10 read it
    if (more) { WAITV(4); } else { WAITV(0); }
    BARF();
    // q11: quad(m4-7, n2-3); stage B-u1(s+1)
    RDA(1, abase);
    MMQ(1, 1);
    if (more) STGU(Bs, s + 1, 64, 192, both);
    // q10: quad(m4-7, n0-1); stage A-u1(s+1)
    RDB(0, bbase);
    MMQ(1, 0);
    if (more) STGU(As, s + 1, 64, 192, aoth);
    // end-wait: land A-u0/B-u0/B-u1(s+1); leave A-u1(s+1) riding
    if (more) { WAITV(2); }
    BARF();
  }

  // epilogue (R2-verified C/D mapping)
  const int r0 = kb * 4;
  const int cc = fr;
#pragma unroll
  for (int m = 0; m < 8; m++) {
#pragma unroll
    for (int n = 0; n < 4; n++) {
      const int col = bn + wn * 64 + n * 16 + cc;
#pragma unroll
      for (int r = 0; r < 4; r++) {
        const int row = bm + wm * 128 + m * 16 + r0 + r;
        const float val = acc[m][n][r];
        if constexpr (EPI == 2) {
          const float xg = val + bias[col];
          const float gel = 0.5f * xg * (1.f + erff(xg * 0.70710678118f));
          h0[(size_t)row * N + col] = (__bf16)gel;
        } else {
          const size_t idx = (size_t)row * N + col;
          f0[idx] = f0[idx] + val + bias[col];
        }
      }
    }
  }
}

// ---------------- attention pass 1 ------------------------------------------
__global__ __launch_bounds__(256) void attn_pass1(const __bf16* __restrict__ q,
                                                  const __bf16* __restrict__ k,
                                                  const float* __restrict__ qsum,
                                                  const float* __restrict__ ksum,
                                                  float* __restrict__ si_out,
                                                  float* __restrict__ qkpart) {
  __shared__ float lsQ[512], lsK[512];
  const int t = threadIdx.x, lane = t & 63, wv = t >> 6;
  const int c0 = lane * 8;
  lsQ[t] = 0.f; lsQ[t + 256] = 0.f;
  lsK[t] = 0.f; lsK[t + 256] = 0.f;
  __syncthreads();
  float qs[8], ks[8];
#pragma unroll
  for (int j = 0; j < 8; j++) {
    qs[j] = qsum[c0 + j] + EPSF;
    ks[j] = ksum[c0 + j] + EPSF;
  }
  const int h = lane >> 3;
  float qacc[8] = {}, kacc[8] = {};
#pragma unroll 1
  for (int i = 0; i < 8; i++) {
    const int l = blockIdx.x * 32 + wv * 8 + i;
    const b16x8 q8 = *reinterpret_cast<const b16x8*>(q + (size_t)l * 512 + c0);
    const b16x8 k8 = *reinterpret_cast<const b16x8*>(k + (size_t)l * 512 + c0);
    float qf[8], kf[8];
    float p1 = 0.f, p2 = 0.f;
#pragma unroll
    for (int j = 0; j < 8; j++) {
      qf[j] = (float)q8[j]; kf[j] = (float)k8[j];
      p1 += (qf[j] + EPSF) * ks[j];
      p2 += (kf[j] + EPSF) * qs[j];
    }
    p1 += __shfl_xor(p1, 1); p2 += __shfl_xor(p2, 1);
    p1 += __shfl_xor(p1, 2); p2 += __shfl_xor(p2, 2);
    p1 += __shfl_xor(p1, 4); p2 += __shfl_xor(p2, 4);
    const float siv = 1.f / p1, sov = 1.f / p2;
    if ((lane & 7) == 0) si_out[h * L_SEQ + l] = siv;
#pragma unroll
    for (int j = 0; j < 8; j++) { qacc[j] += qf[j] * siv; kacc[j] += kf[j] * sov; }
  }
#pragma unroll
  for (int j = 0; j < 8; j++) {
    atomicAdd(&lsQ[c0 + j], qacc[j]);
    atomicAdd(&lsK[c0 + j], kacc[j]);
  }
  __syncthreads();
  float* qp = qkpart + (size_t)blockIdx.x * 1024;
  qp[t] = lsQ[t];
  qp[t + 256] = lsQ[t + 256];
  qp[t + 512] = lsK[t];
  qp[t + 768] = lsK[t + 256];
}

__global__ __launch_bounds__(256) void reduce_qk(const float* __restrict__ qkpart,
                                                 float* __restrict__ outv) {
  const int i = blockIdx.x * 256 + threadIdx.x;
  float s = 0.f;
#pragma unroll 4
  for (int b = 0; b < 512; b++) s += qkpart[(size_t)b * 1024 + i];
  outv[i] = s;
}

// ---------------- kv partials (bf16 v) --------------------------------------
__global__ __launch_bounds__(256) void kv_part(const __bf16* __restrict__ k,
                                               const __bf16* __restrict__ v,
                                               const float* __restrict__ qsi,
                                               float* __restrict__ kvpart,
                                               float* __restrict__ separt) {
  const int h = blockIdx.y, bx = blockIdx.x, t = threadIdx.x;
  __shared__ float lsK[64 * 68];
  __shared__ float lsV[64 * 68];
  __shared__ float lsRed[256];
  const int r = t >> 2, cq = (t & 3) * 16;
  float qv[16];
#pragma unroll
  for (int j = 0; j < 16; j++) qv[j] = qsi[h * 64 + cq + j] + EPSF;
  const int d = t & 63, mg = t >> 6;
  f32x4 acc4[4] = {};
  float seloc = 0.f;
#pragma unroll 1
  for (int sc = 0; sc < 4; sc++) {
    const int l = bx * 256 + sc * 64 + r;
    __syncthreads();
    const b16x8 k8a = *reinterpret_cast<const b16x8*>(k + (size_t)l * 512 + h * 64 + cq);
    const b16x8 k8b = *reinterpret_cast<const b16x8*>(k + (size_t)l * 512 + h * 64 + cq + 8);
    const b16x8 v8a = *reinterpret_cast<const b16x8*>(v + (size_t)l * 512 + h * 64 + cq);
    const b16x8 v8b = *reinterpret_cast<const b16x8*>(v + (size_t)l * 512 + h * 64 + cq + 8);
    float kf[16], vf[16];
#pragma unroll
    for (int j = 0; j < 8; j++) {
      kf[j] = (float)k8a[j]; kf[8 + j] = (float)k8b[j];
      vf[j] = (float)v8a[j]; vf[8 + j] = (float)v8b[j];
    }
    float p = 0.f;
#pragma unroll
    for (int j = 0; j < 16; j++) p += (kf[j] + EPSF) * qv[j];
    p += __shfl_xor(p, 1);
    p += __shfl_xor(p, 2);
    p = fminf(fmaxf(p, -1.f), 1.f);
    const float ce = __expf(p);
    if ((t & 3) == 0) seloc += ce;
#pragma unroll
    for (int j = 0; j < 16; j++) {
      lsK[r * 68 + cq + j] = kf[j];
      lsV[r * 68 + cq + j] = vf[j] * ce;
    }
    __syncthreads();
    for (int rr = 0; rr < 64; rr++) {
      const float kd = lsK[rr * 68 + d];
      const f32x4* lv = reinterpret_cast<const f32x4*>(&lsV[rr * 68 + mg * 16]);
#pragma unroll
      for (int jj = 0; jj < 4; jj++) acc4[jj] += lv[jj] * kd;
    }
  }
  float* kp = kvpart + ((size_t)h * 64 + bx) * 4096;
#pragma unroll
  for (int jj = 0; jj < 4; jj++)
    *reinterpret_cast<f32x4*>(&kp[d * 64 + mg * 16 + jj * 4]) = acc4[jj];
  lsRed[t] = ((t & 3) == 0) ? seloc : 0.f;
  __syncthreads();
  for (int s2 = 128; s2 > 0; s2 >>= 1) {
    if (t < s2) lsRed[t] += lsRed[t + s2];
    __syncthreads();
  }
  if (t == 0) separt[h * 64 + bx] = lsRed[0];
}

__global__ __launch_bounds__(256) void kv_reduce(const float* __restrict__ kvpart,
                                                 const float* __restrict__ separt,
                                                 float* __restrict__ kvout,
                                                 float* __restrict__ sumexp) {
  const int h = blockIdx.y, t = threadIdx.x;
  const int i = blockIdx.x * 256 + t;
  float s = 0.f;
#pragma unroll 4
  for (int b = 0; b < 64; b++) s += kvpart[((size_t)h * 64 + b) * 4096 + i];
  kvout[h * 4096 + i] = s;
  if (blockIdx.x == 0 && t < 64) {
    float e = separt[h * 64 + t];
#pragma unroll
    for (int off2 = 32; off2 > 0; off2 >>= 1) e += __shfl_down(e, off2);
    if (t == 0) sumexp[h] = e;
  }
}

// ---------------- o kernel ---------------------------------------------------
__global__ __launch_bounds__(256) void o_kernel(const __bf16* __restrict__ q,
                                                const float* __restrict__ kvin,
                                                const float* __restrict__ si,
                                                const float* __restrict__ kso,
                                                const float* __restrict__ sumexp,
                                                __bf16* __restrict__ o) {
  const int h = blockIdx.y;
  const int l0 = blockIdx.x * 32;
  const int t = threadIdx.x;
  __shared__ float lsKV[64 * 64];
  __shared__ float lsQ[32 * 65];
  __shared__ float lsF[32];
  const float Sfac = (float)L_SEQ / sumexp[h];
#pragma unroll
  for (int j = 0; j < 16; j++) lsKV[t + j * 256] = kvin[h * 4096 + t + j * 256];
  const int r = t >> 3, c8 = (t & 7) * 8;
  float ksov[8];
#pragma unroll
  for (int j = 0; j < 8; j++) ksov[j] = kso[h * 64 + c8 + j] + EPSF;
  const b16x8 q8 = *reinterpret_cast<const b16x8*>(q + (size_t)(l0 + r) * 512 + h * 64 + c8);
  float p = 0.f;
#pragma unroll
  for (int j = 0; j < 8; j++) {
    const float qf = (float)q8[j];
    lsQ[r * 65 + c8 + j] = qf;
    p += (qf + EPSF) * ksov[j];
  }
  p += __shfl_xor(p, 1);
  p += __shfl_xor(p, 2);
  p += __shfl_xor(p, 4);
  if ((t & 7) == 0) lsF[r] = sigmoidf_(p) * si[h * L_SEQ + l0 + r] * Sfac;
  __syncthreads();
  const int m = t & 63, rg = t >> 6;
#pragma unroll 1
  for (int i = 0; i < 8; i++) {
    const int rr = rg + i * 4;
    float a = 0.f;
#pragma unroll
    for (int dd = 0; dd < 64; dd++) a += lsQ[rr * 65 + dd] * lsKV[dd * 64 + m];
    o[(size_t)(l0 + rr) * 512 + h * 64 + m] = (__bf16)(a * lsF[rr]);
  }
}

// ---------------------------------------------------------------------------
extern "C" void kernel_launch(void* const* d_in, const int* in_sizes, int n_in,
                              void* d_out, int out_size, void* d_ws, size_t ws_size,
                              hipStream_t stream) {
  const float* x  = (const float*)d_in[0];
  const float* Wq = (const float*)d_in[1];
  const float* bq = (const float*)d_in[2];
  const float* Wk = (const float*)d_in[3];
  const float* bk = (const float*)d_in[4];
  const float* Wv = (const float*)d_in[5];
  const float* bv = (const float*)d_in[6];
  const float* Wo = (const float*)d_in[7];
  const float* bo = (const float*)d_in[8];
  const float* W1 = (const float*)d_in[9];
  const float* b1 = (const float*)d_in[10];
  const float* W2 = (const float*)d_in[11];
  const float* b2 = (const float*)d_in[12];
  const float* g1 = (const float*)d_in[13];
  const float* be1 = (const float*)d_in[14];
  const float* g2 = (const float*)d_in[15];
  const float* be2 = (const float*)d_in[16];
  float* out = (float*)d_out;

  char* ws = (char*)d_ws;
  size_t off = 0;
  auto alloc = [&](size_t bytes) -> char* {
    char* p = ws + off;
    off += (bytes + 255) & ~(size_t)255;
    return p;
  };

  char* regA = alloc(134217728);
  __bf16* ln1  = (__bf16*)regA;
  __bf16* qb16 = (__bf16*)(regA + 16777216);
  __bf16* kb16 = (__bf16*)(regA + 33554432);
  __bf16* vb16 = (__bf16*)(regA + 50331648);
  __bf16* ob   = (__bf16*)(regA + 83886080);
  float*  sa   = (float*)regA;
  __bf16* act  = (__bf16*)regA;

  __bf16* ln2 = (__bf16*)alloc((size_t)32768 * 512 * 2);
  __bf16* Wqkvt = (__bf16*)alloc((size_t)1536 * 512 * 2);
  __bf16* Wot = (__bf16*)alloc((size_t)512 * 512 * 2);
  __bf16* W1t = (__bf16*)alloc((size_t)2048 * 512 * 2);
  __bf16* W2t = (__bf16*)alloc((size_t)512 * 2048 * 2);
  float* biascat = (float*)alloc(1536 * 4);
  float* si = (float*)alloc((size_t)8 * L_SEQ * 4);
  float* stats = (float*)alloc(34880 * 4);
  float* qsum = stats;
  float* ksum = stats + 512;
  float* qsi = stats + 1024;
  float* kso = stats + 1536;
  float* sumexp = stats + 2048;
  float* kvbuf = stats + 2112;
  float* kvpart = (float*)alloc((size_t)8 * 64 * 4096 * 4);
  float* separt = (float*)alloc(512 * 4);
  float* qkpart = (float*)alloc((size_t)512 * 1024 * 4);

  convT<<<dim3(16, 16), 256, 0, stream>>>(Wq, Wqkvt, 512, 512);
  convT<<<dim3(16, 16), 256, 0, stream>>>(Wk, Wqkvt + (size_t)512 * 512, 512, 512);
  convT<<<dim3(16, 16), 256, 0, stream>>>(Wv, Wqkvt + (size_t)1024 * 512, 512, 512);
  convT<<<dim3(16, 16), 256, 0, stream>>>(Wo, Wot, 512, 512);
  convT<<<dim3(64, 16), 256, 0, stream>>>(W1, W1t, 512, 2048);
  convT<<<dim3(16, 64), 256, 0, stream>>>(W2, W2t, 2048, 512);
  biascat_k<<<6, 256, 0, stream>>>(bq, bk, bv, biascat);
  zero_k<<<(2112 + 255) / 256, 256, 0, stream>>>(stats, 2112);

  ln_rows<<<L_SEQ, 128, 0, stream>>>(x, g1, be1, ln1);
  gemm128<0, 0><<<1536, 256, 0, stream>>>(ln1, Wqkvt, L_SEQ, 1536, 512,
                                          biascat, (float*)vb16, qb16, kb16, qsum, ksum);

  attn_pass1<<<512, 256, 0, stream>>>(qb16, kb16, qsum, ksum, si, qkpart);
  reduce_qk<<<4, 256, 0, stream>>>(qkpart, qsi);
  kv_part<<<dim3(64, 8), 256, 0, stream>>>(kb16, vb16, qsi, kvpart, separt);
  kv_reduce<<<dim3(16, 8), 256, 0, stream>>>(kvpart, separt, kvbuf, sumexp);
  o_kernel<<<dim3(L_SEQ / 32, 8), 256, 0, stream>>>(qb16, kvbuf, si, kso, sumexp, ob);

  gemm128<1, 1><<<dim3(512, 2), 256, 0, stream>>>(ob, Wot, L_SEQ, 512, 512,
                                                  nullptr, sa, nullptr, nullptr,
                                                  nullptr, nullptr);

  x2ln2_k<<<2 * L_SEQ, 128, 0, stream>>>(x, sa, sa + (size_t)L_SEQ * 512, bo,
                                         g2, be2, out, ln2);

  // MLP via 4-phase zigzag 256^2 kernels
  gemm256z<2><<<1024, 512, 0, stream>>>(ln2, W1t, 2 * L_SEQ, 2048, 512,
                                        b1, nullptr, act);
  gemm256z<3><<<256, 512, 0, stream>>>(act, W2t, 2 * L_SEQ, 512, 2048,
                                       b2, out, nullptr);
}

// Round 12
// 498.650 us; speedup vs baseline: 1.1489x; 1.0725x over previous
//
#include <hip/hip_runtime.h>
#include <hip/hip_bf16.h>
#include <cstdint>
#include <cstddef>

// ---------------------------------------------------------------------------
// FlowformerLayer: LN1 -> flow-attention(batch0) -> +res -> LN2 -> MLP -> +res
// B=2, L=16384, D=512, H=8, DH=64, F=2048
// All GEMMs: R6 gemm128 (best measured total, 514us): 128x128, BK=32,
//   4 waves, dbuf 32KB, 1 barrier/K-tile, 4 blocks/CU.
//   (R2..R11 structural matrix — phase count x prefetch depth x occupancy x
//    MFMA shape — all plateau at 18-21% MfmaUtil; reverting to best total.)
// prep_k: fused weight-convert/transpose + biascat + stats-zero (8 launches->1).
// Attention: 3 passes over bf16 q/k/v, slab-reduced (no contended atomics).
// ---------------------------------------------------------------------------

#define L_SEQ 16384
#define EPSF 1e-6f

typedef __bf16 b16x8 __attribute__((ext_vector_type(8)));
typedef __bf16 b16x4 __attribute__((ext_vector_type(4)));
typedef float  f32x4 __attribute__((ext_vector_type(4)));

#define FENCE() asm volatile("" ::: "memory")
#define BARF()  { FENCE(); __builtin_amdgcn_s_barrier(); FENCE(); }
#define WAITV(n) asm volatile("s_waitcnt vmcnt(" #n ")" ::: "memory")

__device__ __forceinline__ void gload16(const void* g, void* l) {
  __builtin_amdgcn_global_load_lds((const __attribute__((address_space(1))) void*)g,
                                   (__attribute__((address_space(3))) void*)l, 16, 0, 0);
}

__device__ __forceinline__ float sigmoidf_(float x) { return 1.f / (1.f + __expf(-x)); }

// ---------------- prep: all weight transposes + biascat + zeroing, 1 launch
// blocks [0,3072): 32x32 convT tiles across 6 weights; [3072,3087): misc.
__global__ __launch_bounds__(256) void prep_k(const float* __restrict__ Wq,
                                              const float* __restrict__ Wk,
                                              const float* __restrict__ Wv,
                                              const float* __restrict__ Wo,
                                              const float* __restrict__ W1,
                                              const float* __restrict__ W2,
                                              const float* __restrict__ bq,
                                              const float* __restrict__ bk,
                                              const float* __restrict__ bv,
                                              __bf16* __restrict__ Wqkvt,
                                              __bf16* __restrict__ Wot,
                                              __bf16* __restrict__ W1t,
                                              __bf16* __restrict__ W2t,
                                              float* __restrict__ biascat,
                                              float* __restrict__ zstats) {
  const int b = blockIdx.x;
  if (b >= 3072) {
    const int i = (b - 3072) * 256 + threadIdx.x;
    if (i < 1536) biascat[i] = (i < 512) ? bq[i] : (i < 1024) ? bk[i - 512] : bv[i - 1024];
    else if (i < 1536 + 2112) zstats[i - 1536] = 0.f;
    return;
  }
  const float* src;
  __bf16* dst;
  int K, N, bx, by;
  if (b < 256)       { src = Wq; dst = Wqkvt;                      K = 512;  N = 512;  const int r = b;        bx = r & 15; by = r >> 4; }
  else if (b < 512)  { src = Wk; dst = Wqkvt + (size_t)512 * 512;  K = 512;  N = 512;  const int r = b - 256;  bx = r & 15; by = r >> 4; }
  else if (b < 768)  { src = Wv; dst = Wqkvt + (size_t)1024 * 512; K = 512;  N = 512;  const int r = b - 512;  bx = r & 15; by = r >> 4; }
  else if (b < 1024) { src = Wo; dst = Wot;                        K = 512;  N = 512;  const int r = b - 768;  bx = r & 15; by = r >> 4; }
  else if (b < 2048) { src = W1; dst = W1t;                        K = 512;  N = 2048; const int r = b - 1024; bx = r & 63; by = r >> 6; }
  else               { src = W2; dst = W2t;                        K = 2048; N = 512;  const int r = b - 2048; bx = r & 15; by = r >> 4; }
  __shared__ float tile[32][33];
  const int k0 = by * 32, n0 = bx * 32;
  const int tx = threadIdx.x & 31, ty = threadIdx.x >> 5;
#pragma unroll
  for (int i = 0; i < 32; i += 8) tile[ty + i][tx] = src[(size_t)(k0 + ty + i) * N + n0 + tx];
  __syncthreads();
#pragma unroll
  for (int i = 0; i < 32; i += 8)
    dst[(size_t)(n0 + ty + i) * K + k0 + tx] = (__bf16)tile[tx][ty + i];
}

// ---------------- LayerNorm over D=512, one row per block
__global__ __launch_bounds__(128) void ln_rows(const float* __restrict__ x,
                                               const float* __restrict__ g,
                                               const float* __restrict__ be,
                                               __bf16* __restrict__ out) {
  const int row = blockIdx.x, t = threadIdx.x;
  const float4 xv = reinterpret_cast<const float4*>(x + (size_t)row * 512)[t];
  float s = xv.x + xv.y + xv.z + xv.w;
  float s2 = xv.x * xv.x + xv.y * xv.y + xv.z * xv.z + xv.w * xv.w;
#pragma unroll
  for (int off = 32; off > 0; off >>= 1) { s += __shfl_down(s, off); s2 += __shfl_down(s2, off); }
  __shared__ float red[4];
  if ((t & 63) == 0) { red[(t >> 6) * 2] = s; red[(t >> 6) * 2 + 1] = s2; }
  __syncthreads();
  const float S = red[0] + red[2], S2 = red[1] + red[3];
  const float mean = S * (1.f / 512.f);
  const float var = S2 * (1.f / 512.f) - mean * mean;
  const float inv = rsqrtf(var + 1e-5f);
  const float4 gv = reinterpret_cast<const float4*>(g)[t];
  const float4 bv = reinterpret_cast<const float4*>(be)[t];
  b16x4 o;
  o[0] = (__bf16)((xv.x - mean) * inv * gv.x + bv.x);
  o[1] = (__bf16)((xv.y - mean) * inv * gv.y + bv.y);
  o[2] = (__bf16)((xv.z - mean) * inv * gv.z + bv.z);
  o[3] = (__bf16)((xv.w - mean) * inv * gv.w + bv.w);
  reinterpret_cast<b16x4*>(out + (size_t)row * 512)[t] = o;
}

// ---------------- x2 = x + sa0 + sa1 + bo; d_out=x2; ln2=LN(x2)
__global__ __launch_bounds__(128) void x2ln2_k(const float* __restrict__ x,
                                               const float* __restrict__ sa0,
                                               const float* __restrict__ sa1,
                                               const float* __restrict__ bo,
                                               const float* __restrict__ g,
                                               const float* __restrict__ be,
                                               float* __restrict__ xout,
                                               __bf16* __restrict__ lnout) {
  const int row = blockIdx.x, t = threadIdx.x;
  const int l = row & (L_SEQ - 1);
  float4 xv = reinterpret_cast<const float4*>(x + (size_t)row * 512)[t];
  const float4 s0 = reinterpret_cast<const float4*>(sa0 + (size_t)l * 512)[t];
  const float4 s1 = reinterpret_cast<const float4*>(sa1 + (size_t)l * 512)[t];
  const float4 bb = reinterpret_cast<const float4*>(bo)[t];
  xv.x += s0.x + s1.x + bb.x; xv.y += s0.y + s1.y + bb.y;
  xv.z += s0.z + s1.z + bb.z; xv.w += s0.w + s1.w + bb.w;
  reinterpret_cast<float4*>(xout + (size_t)row * 512)[t] = xv;
  float s = xv.x + xv.y + xv.z + xv.w;
  float s2 = xv.x * xv.x + xv.y * xv.y + xv.z * xv.z + xv.w * xv.w;
#pragma unroll
  for (int off = 32; off > 0; off >>= 1) { s += __shfl_down(s, off); s2 += __shfl_down(s2, off); }
  __shared__ float red[4];
  if ((t & 63) == 0) { red[(t >> 6) * 2] = s; red[(t >> 6) * 2 + 1] = s2; }
  __syncthreads();
  const float S = red[0] + red[2], S2 = red[1] + red[3];
  const float mean = S * (1.f / 512.f);
  const float var = S2 * (1.f / 512.f) - mean * mean;
  const float inv = rsqrtf(var + 1e-5f);
  const float4 gv = reinterpret_cast<const float4*>(g)[t];
  const float4 bv = reinterpret_cast<const float4*>(be)[t];
  b16x4 o;
  o[0] = (__bf16)((xv.x - mean) * inv * gv.x + bv.x);
  o[1] = (__bf16)((xv.y - mean) * inv * gv.y + bv.y);
  o[2] = (__bf16)((xv.z - mean) * inv * gv.z + bv.z);
  o[3] = (__bf16)((xv.w - mean) * inv * gv.w + bv.w);
  reinterpret_cast<b16x4*>(lnout + (size_t)row * 512)[t] = o;
}

// ---------------- gemm128 (R6 config): all GEMMs ----------------------------
// EPI 0: QKV (+biascat, sigmoid q/k -> bf16 h0/h1 + colsums f1/f2; v -> bf16 f0)
// EPI 1: SA  (val only -> f0, split-K via blockIdx.y)
// EPI 2: GELU(+bias -> bf16 h0, stride N)
// EPI 3: OUT (f0[row,col] += acc + bias)
template <int EPI, int KSPL>
__global__ __launch_bounds__(256, 4) void gemm128(const __bf16* __restrict__ A,
                                                  const __bf16* __restrict__ Bt,
                                                  const int M, const int N, const int K,
                                                  const float* __restrict__ bias,
                                                  float* __restrict__ f0,
                                                  __bf16* __restrict__ h0,
                                                  __bf16* __restrict__ h1,
                                                  float* __restrict__ f1,
                                                  float* __restrict__ f2) {
  __shared__ alignas(16) __bf16 lds[16384];  // 32 KB

  if constexpr (KSPL) {
    const int z = blockIdx.y;
    A += (size_t)z * (K >> 1);
    Bt += (size_t)z * (K >> 1);
    f0 += (size_t)z * ((size_t)M * N);
  }
  const int nt = KSPL ? (K >> 6) : (K >> 5);

  const int nwg = gridDim.x;
  const int orig = blockIdx.x;
  const int cpx = nwg >> 3;
  const int wg = (orig & 7) * cpx + (orig >> 3);
  const int gx = N >> 7;
  const int bm = (wg / gx) << 7;
  const int bn = (wg % gx) << 7;

  const int t = threadIdx.x;
  const int w = t >> 6, lane = t & 63;
  const int wr = w >> 1, wc = w & 1;
  const int fr = lane & 15;
  const int kb = lane >> 4;

  const __bf16* As = A + (size_t)(bm + (t >> 2)) * K + (t & 3) * 8;
  const __bf16* Bs = Bt + (size_t)(bn + (t >> 2)) * K + (t & 3) * 8;

  f32x4 acc[4][4] = {};

  auto STG = [&](int s) {
    const int sel = (s & 1) * 4096;
    const __bf16* ap = As + (s << 5);
    const __bf16* bp = Bs + (s << 5);
    gload16(ap, &lds[sel + t * 8]);
    gload16(ap + (size_t)64 * K, &lds[sel + 2048 + t * 8]);
    gload16(bp, &lds[8192 + sel + t * 8]);
    gload16(bp + (size_t)64 * K, &lds[8192 + sel + 2048 + t * 8]);
  };

  STG(0);
  WAITV(0);
  BARF();

  for (int s = 0; s < nt; s++) {
    if (s + 1 < nt) STG(s + 1);
    const int ab = (s & 1) * 4096 + (wr * 64 + fr) * 32 + kb * 8;
    const int bb2 = 8192 + (s & 1) * 4096 + (wc * 64 + fr) * 32 + kb * 8;
    b16x8 av[4], bv[4];
#pragma unroll
    for (int m = 0; m < 4; m++)
      av[m] = *reinterpret_cast<const b16x8*>(&lds[ab + m * 512]);
#pragma unroll
    for (int n = 0; n < 4; n++)
      bv[n] = *reinterpret_cast<const b16x8*>(&lds[bb2 + n * 512]);
#pragma unroll
    for (int m = 0; m < 4; m++)
#pragma unroll
      for (int n = 0; n < 4; n++)
        acc[m][n] = __builtin_amdgcn_mfma_f32_16x16x32_bf16(av[m], bv[n], acc[m][n], 0, 0, 0);
    WAITV(0);
    BARF();
  }

  const int r0 = kb * 4;
  const int cc = fr;
  if constexpr (EPI == 0) {
    const int which = bn >> 9;  // 0=q, 1=k, 2=v
    float cs[4] = {0.f, 0.f, 0.f, 0.f};
#pragma unroll
    for (int m = 0; m < 4; m++) {
#pragma unroll
      for (int n = 0; n < 4; n++) {
        const int col = bn + wc * 64 + n * 16 + cc;
        const int c2 = col & 511;
#pragma unroll
        for (int r = 0; r < 4; r++) {
          const int row = bm + wr * 64 + m * 16 + r0 + r;
          float val = acc[m][n][r] + bias[col];
          if (which < 2) {
            val = sigmoidf_(val);
            cs[n] += val;
            ((which == 0) ? h0 : h1)[(size_t)row * 512 + c2] = (__bf16)val;
          } else {
            ((__bf16*)f0)[(size_t)row * 512 + c2] = (__bf16)val;  // v as bf16
          }
        }
      }
    }
    if (which < 2) {
      float* sums = (which == 0) ? f1 : f2;
#pragma unroll
      for (int n = 0; n < 4; n++) {
        float s = cs[n];
        s += __shfl_xor(s, 16);
        s += __shfl_xor(s, 32);
        if (kb == 0) atomicAdd(&sums[(bn & 511) + wc * 64 + n * 16 + cc], s);
      }
    }
  } else {
#pragma unroll
    for (int m = 0; m < 4; m++) {
#pragma unroll
      for (int n = 0; n < 4; n++) {
        const int col = bn + wc * 64 + n * 16 + cc;
#pragma unroll
        for (int r = 0; r < 4; r++) {
          const int row = bm + wr * 64 + m * 16 + r0 + r;
          const float val = acc[m][n][r];
          if constexpr (EPI == 1) {
            f0[(size_t)row * N + col] = val;
          } else if constexpr (EPI == 2) {
            const float xg = val + bias[col];
            const float gel = 0.5f * xg * (1.f + erff(xg * 0.70710678118f));
            h0[(size_t)row * N + col] = (__bf16)gel;
          } else {
            const size_t idx = (size_t)row * N + col;
            f0[idx] = f0[idx] + val + bias[col];
          }
        }
      }
    }
  }
}

// ---------------- attention pass 1 ------------------------------------------
__global__ __launch_bounds__(256) void attn_pass1(const __bf16* __restrict__ q,
                                                  const __bf16* __restrict__ k,
                                                  const float* __restrict__ qsum,
                                                  const float* __restrict__ ksum,
                                                  float* __restrict__ si_out,
                                                  float* __restrict__ qkpart) {
  __shared__ float lsQ[512], lsK[512];
  const int t = threadIdx.x, lane = t & 63, wv = t >> 6;
  const int c0 = lane * 8;
  lsQ[t] = 0.f; lsQ[t + 256] = 0.f;
  lsK[t] = 0.f; lsK[t + 256] = 0.f;
  __syncthreads();
  float qs[8], ks[8];
#pragma unroll
  for (int j = 0; j < 8; j++) {
    qs[j] = qsum[c0 + j] + EPSF;
    ks[j] = ksum[c0 + j] + EPSF;
  }
  const int h = lane >> 3;
  float qacc[8] = {}, kacc[8] = {};
#pragma unroll 1
  for (int i = 0; i < 8; i++) {
    const int l = blockIdx.x * 32 + wv * 8 + i;
    const b16x8 q8 = *reinterpret_cast<const b16x8*>(q + (size_t)l * 512 + c0);
    const b16x8 k8 = *reinterpret_cast<const b16x8*>(k + (size_t)l * 512 + c0);
    float qf[8], kf[8];
    float p1 = 0.f, p2 = 0.f;
#pragma unroll
    for (int j = 0; j < 8; j++) {
      qf[j] = (float)q8[j]; kf[j] = (float)k8[j];
      p1 += (qf[j] + EPSF) * ks[j];
      p2 += (kf[j] + EPSF) * qs[j];
    }
    p1 += __shfl_xor(p1, 1); p2 += __shfl_xor(p2, 1);
    p1 += __shfl_xor(p1, 2); p2 += __shfl_xor(p2, 2);
    p1 += __shfl_xor(p1, 4); p2 += __shfl_xor(p2, 4);
    const float siv = 1.f / p1, sov = 1.f / p2;
    if ((lane & 7) == 0) si_out[h * L_SEQ + l] = siv;
#pragma unroll
    for (int j = 0; j < 8; j++) { qacc[j] += qf[j] * siv; kacc[j] += kf[j] * sov; }
  }
#pragma unroll
  for (int j = 0; j < 8; j++) {
    atomicAdd(&lsQ[c0 + j], qacc[j]);
    atomicAdd(&lsK[c0 + j], kacc[j]);
  }
  __syncthreads();
  float* qp = qkpart + (size_t)blockIdx.x * 1024;
  qp[t] = lsQ[t];
  qp[t + 256] = lsQ[t + 256];
  qp[t + 512] = lsK[t];
  qp[t + 768] = lsK[t + 256];
}

__global__ __launch_bounds__(256) void reduce_qk(const float* __restrict__ qkpart,
                                                 float* __restrict__ outv) {
  const int i = blockIdx.x * 256 + threadIdx.x;
  float s = 0.f;
#pragma unroll 4
  for (int b = 0; b < 512; b++) s += qkpart[(size_t)b * 1024 + i];
  outv[i] = s;
}

// ---------------- kv partials (bf16 v) --------------------------------------
__global__ __launch_bounds__(256) void kv_part(const __bf16* __restrict__ k,
                                               const __bf16* __restrict__ v,
                                               const float* __restrict__ qsi,
                                               float* __restrict__ kvpart,
                                               float* __restrict__ separt) {
  const int h = blockIdx.y, bx = blockIdx.x, t = threadIdx.x;
  __shared__ float lsK[64 * 68];
  __shared__ float lsV[64 * 68];
  __shared__ float lsRed[256];
  const int r = t >> 2, cq = (t & 3) * 16;
  float qv[16];
#pragma unroll
  for (int j = 0; j < 16; j++) qv[j] = qsi[h * 64 + cq + j] + EPSF;
  const int d = t & 63, mg = t >> 6;
  f32x4 acc4[4] = {};
  float seloc = 0.f;
#pragma unroll 1
  for (int sc = 0; sc < 4; sc++) {
    const int l = bx * 256 + sc * 64 + r;
    __syncthreads();
    const b16x8 k8a = *reinterpret_cast<const b16x8*>(k + (size_t)l * 512 + h * 64 + cq);
    const b16x8 k8b = *reinterpret_cast<const b16x8*>(k + (size_t)l * 512 + h * 64 + cq + 8);
    const b16x8 v8a = *reinterpret_cast<const b16x8*>(v + (size_t)l * 512 + h * 64 + cq);
    const b16x8 v8b = *reinterpret_cast<const b16x8*>(v + (size_t)l * 512 + h * 64 + cq + 8);
    float kf[16], vf[16];
#pragma unroll
    for (int j = 0; j < 8; j++) {
      kf[j] = (float)k8a[j]; kf[8 + j] = (float)k8b[j];
      vf[j] = (float)v8a[j]; vf[8 + j] = (float)v8b[j];
    }
    float p = 0.f;
#pragma unroll
    for (int j = 0; j < 16; j++) p += (kf[j] + EPSF) * qv[j];
    p += __shfl_xor(p, 1);
    p += __shfl_xor(p, 2);
    p = fminf(fmaxf(p, -1.f), 1.f);
    const float ce = __expf(p);
    if ((t & 3) == 0) seloc += ce;
#pragma unroll
    for (int j = 0; j < 16; j++) {
      lsK[r * 68 + cq + j] = kf[j];
      lsV[r * 68 + cq + j] = vf[j] * ce;
    }
    __syncthreads();
    for (int rr = 0; rr < 64; rr++) {
      const float kd = lsK[rr * 68 + d];
      const f32x4* lv = reinterpret_cast<const f32x4*>(&lsV[rr * 68 + mg * 16]);
#pragma unroll
      for (int jj = 0; jj < 4; jj++) acc4[jj] += lv[jj] * kd;
    }
  }
  float* kp = kvpart + ((size_t)h * 64 + bx) * 4096;
#pragma unroll
  for (int jj = 0; jj < 4; jj++)
    *reinterpret_cast<f32x4*>(&kp[d * 64 + mg * 16 + jj * 4]) = acc4[jj];
  lsRed[t] = ((t & 3) == 0) ? seloc : 0.f;
  __syncthreads();
  for (int s2 = 128; s2 > 0; s2 >>= 1) {
    if (t < s2) lsRed[t] += lsRed[t + s2];
    __syncthreads();
  }
  if (t == 0) separt[h * 64 + bx] = lsRed[0];
}

__global__ __launch_bounds__(256) void kv_reduce(const float* __restrict__ kvpart,
                                                 const float* __restrict__ separt,
                                                 float* __restrict__ kvout,
                                                 float* __restrict__ sumexp) {
  const int h = blockIdx.y, t = threadIdx.x;
  const int i = blockIdx.x * 256 + t;
  float s = 0.f;
#pragma unroll 4
  for (int b = 0; b < 64; b++) s += kvpart[((size_t)h * 64 + b) * 4096 + i];
  kvout[h * 4096 + i] = s;
  if (blockIdx.x == 0 && t < 64) {
    float e = separt[h * 64 + t];
#pragma unroll
    for (int off2 = 32; off2 > 0; off2 >>= 1) e += __shfl_down(e, off2);
    if (t == 0) sumexp[h] = e;
  }
}

// ---------------- o kernel ---------------------------------------------------
__global__ __launch_bounds__(256) void o_kernel(const __bf16* __restrict__ q,
                                                const float* __restrict__ kvin,
                                                const float* __restrict__ si,
                                                const float* __restrict__ kso,
                                                const float* __restrict__ sumexp,
                                                __bf16* __restrict__ o) {
  const int h = blockIdx.y;
  const int l0 = blockIdx.x * 32;
  const int t = threadIdx.x;
  __shared__ float lsKV[64 * 64];
  __shared__ float lsQ[32 * 65];
  __shared__ float lsF[32];
  const float Sfac = (float)L_SEQ / sumexp[h];
#pragma unroll
  for (int j = 0; j < 16; j++) lsKV[t + j * 256] = kvin[h * 4096 + t + j * 256];
  const int r = t >> 3, c8 = (t & 7) * 8;
  float ksov[8];
#pragma unroll
  for (int j = 0; j < 8; j++) ksov[j] = kso[h * 64 + c8 + j] + EPSF;
  const b16x8 q8 = *reinterpret_cast<const b16x8*>(q + (size_t)(l0 + r) * 512 + h * 64 + c8);
  float p = 0.f;
#pragma unroll
  for (int j = 0; j < 8; j++) {
    const float qf = (float)q8[j];
    lsQ[r * 65 + c8 + j] = qf;
    p += (qf + EPSF) * ksov[j];
  }
  p += __shfl_xor(p, 1);
  p += __shfl_xor(p, 2);
  p += __shfl_xor(p, 4);
  if ((t & 7) == 0) lsF[r] = sigmoidf_(p) * si[h * L_SEQ + l0 + r] * Sfac;
  __syncthreads();
  const int m = t & 63, rg = t >> 6;
#pragma unroll 1
  for (int i = 0; i < 8; i++) {
    const int rr = rg + i * 4;
    float a = 0.f;
#pragma unroll
    for (int dd = 0; dd < 64; dd++) a += lsQ[rr * 65 + dd] * lsKV[dd * 64 + m];
    o[(size_t)(l0 + rr) * 512 + h * 64 + m] = (__bf16)(a * lsF[rr]);
  }
}

// ---------------------------------------------------------------------------
extern "C" void kernel_launch(void* const* d_in, const int* in_sizes, int n_in,
                              void* d_out, int out_size, void* d_ws, size_t ws_size,
                              hipStream_t stream) {
  const float* x  = (const float*)d_in[0];
  const float* Wq = (const float*)d_in[1];
  const float* bq = (const float*)d_in[2];
  const float* Wk = (const float*)d_in[3];
  const float* bk = (const float*)d_in[4];
  const float* Wv = (const float*)d_in[5];
  const float* bv = (const float*)d_in[6];
  const float* Wo = (const float*)d_in[7];
  const float* bo = (const float*)d_in[8];
  const float* W1 = (const float*)d_in[9];
  const float* b1 = (const float*)d_in[10];
  const float* W2 = (const float*)d_in[11];
  const float* b2 = (const float*)d_in[12];
  const float* g1 = (const float*)d_in[13];
  const float* be1 = (const float*)d_in[14];
  const float* g2 = (const float*)d_in[15];
  const float* be2 = (const float*)d_in[16];
  float* out = (float*)d_out;

  char* ws = (char*)d_ws;
  size_t off = 0;
  auto alloc = [&](size_t bytes) -> char* {
    char* p = ws + off;
    off += (bytes + 255) & ~(size_t)255;
    return p;
  };

  char* regA = alloc(134217728);
  __bf16* ln1  = (__bf16*)regA;
  __bf16* qb16 = (__bf16*)(regA + 16777216);
  __bf16* kb16 = (__bf16*)(regA + 33554432);
  __bf16* vb16 = (__bf16*)(regA + 50331648);
  __bf16* ob   = (__bf16*)(regA + 83886080);
  float*  sa   = (float*)regA;
  __bf16* act  = (__bf16*)regA;

  __bf16* ln2 = (__bf16*)alloc((size_t)32768 * 512 * 2);
  __bf16* Wqkvt = (__bf16*)alloc((size_t)1536 * 512 * 2);
  __bf16* Wot = (__bf16*)alloc((size_t)512 * 512 * 2);
  __bf16* W1t = (__bf16*)alloc((size_t)2048 * 512 * 2);
  __bf16* W2t = (__bf16*)alloc((size_t)512 * 2048 * 2);
  float* biascat = (float*)alloc(1536 * 4);
  float* si = (float*)alloc((size_t)8 * L_SEQ * 4);
  float* stats = (float*)alloc(34880 * 4);
  float* qsum = stats;
  float* ksum = stats + 512;
  float* qsi = stats + 1024;
  float* kso = stats + 1536;
  float* sumexp = stats + 2048;
  float* kvbuf = stats + 2112;
  float* kvpart = (float*)alloc((size_t)8 * 64 * 4096 * 4);
  float* separt = (float*)alloc(512 * 4);
  float* qkpart = (float*)alloc((size_t)512 * 1024 * 4);

  // fused prep: 6 weight transposes + biascat + stats zero
  prep_k<<<3087, 256, 0, stream>>>(Wq, Wk, Wv, Wo, W1, W2, bq, bk, bv,
                                   Wqkvt, Wot, W1t, W2t, biascat, stats);

  ln_rows<<<L_SEQ, 128, 0, stream>>>(x, g1, be1, ln1);
  gemm128<0, 0><<<1536, 256, 0, stream>>>(ln1, Wqkvt, L_SEQ, 1536, 512,
                                          biascat, (float*)vb16, qb16, kb16, qsum, ksum);

  attn_pass1<<<512, 256, 0, stream>>>(qb16, kb16, qsum, ksum, si, qkpart);
  reduce_qk<<<4, 256, 0, stream>>>(qkpart, qsi);
  kv_part<<<dim3(64, 8), 256, 0, stream>>>(kb16, vb16, qsi, kvpart, separt);
  kv_reduce<<<dim3(16, 8), 256, 0, stream>>>(kvpart, separt, kvbuf, sumexp);
  o_kernel<<<dim3(L_SEQ / 32, 8), 256, 0, stream>>>(qb16, kvbuf, si, kso, sumexp, ob);

  gemm128<1, 1><<<dim3(512, 2), 256, 0, stream>>>(ob, Wot, L_SEQ, 512, 512,
                                                  nullptr, sa, nullptr, nullptr,
                                                  nullptr, nullptr);

  x2ln2_k<<<2 * L_SEQ, 128, 0, stream>>>(x, sa, sa + (size_t)L_SEQ * 512, bo,
                                         g2, be2, out, ln2);

  // MLP: act = gelu(ln2 @ W1 + b1);  d_out += act @ W2 + b2
  gemm128<2, 0><<<4096, 256, 0, stream>>>(ln2, W1t, 2 * L_SEQ, 2048, 512,
                                          b1, nullptr, act, nullptr, nullptr, nullptr);
  gemm128<3, 0><<<1024, 256, 0, stream>>>(act, W2t, 2 * L_SEQ, 512, 2048,
                                          b2, out, nullptr, nullptr, nullptr, nullptr);
}